// Round 3
// baseline (281.440 us; speedup 1.0000x reference)
//
#include <hip/hip_runtime.h>
#include <math.h>

#define BB 8192
#define KK 6
#define EE 5    // K-1
#define CC 1000
#define NV4 250 // CC/4 float4 per row

// ---------------- Kernel A: cross-entropy per (b,k) row --------------------
// One wave (64 lanes) per row of 1000 fp32 logits; 4 waves per 256-thread
// block (full 32-wave/CU occupancy). Each lane holds up to 4 float4
// (16 floats) in registers -> single HBM pass for max + sum-exp.
__global__ __launch_bounds__(256) void ce_kernel(
    const float* __restrict__ yh, const int* __restrict__ ys,
    float* __restrict__ ce)
{
    const int wid  = (blockIdx.x * 256 + threadIdx.x) >> 6;   // row id = b*K+k
    const int lane = threadIdx.x & 63;
    const size_t row = (size_t)wid * CC;
    const float4* rp = (const float4*)(yh + row);

    // issue the target-logit broadcast load early (latency overlaps compute)
    const int   y  = ys[wid];
    const float xy = yh[row + (size_t)y];

    const float NEG = -__builtin_inff();
    float4 r[4];
#pragma unroll
    for (int i = 0; i < 4; ++i) {
        const int idx = lane + 64 * i;
        if (idx < NV4) r[i] = rp[idx];
        else           r[i] = make_float4(NEG, NEG, NEG, NEG);
    }

    // row max
    float mx = NEG;
#pragma unroll
    for (int i = 0; i < 4; ++i)
        mx = fmaxf(mx, fmaxf(fmaxf(r[i].x, r[i].y), fmaxf(r[i].z, r[i].w)));
#pragma unroll
    for (int off = 32; off > 0; off >>= 1)
        mx = fmaxf(mx, __shfl_xor(mx, off));

    // sum exp(x - max); exp(-inf - mx) = 0 handles the 6 pad slots
    float s = 0.f;
#pragma unroll
    for (int i = 0; i < 4; ++i) {
        s += __expf(r[i].x - mx);
        s += __expf(r[i].y - mx);
        s += __expf(r[i].z - mx);
        s += __expf(r[i].w - mx);
    }
#pragma unroll
    for (int off = 32; off > 0; off >>= 1)
        s += __shfl_xor(s, off);

    if (lane == 0) ce[wid] = mx + __logf(s) - xy;
}

// -------- Kernel B: gate recurrence + exit cost + full reduction -----------
// Single block, 1024 threads (16 waves). Deterministic: no memset, no
// atomics. Reads ce (192 KB) + g (160 KB), both L2-resident from kernel A.
__global__ __launch_bounds__(1024) void gate_reduce_kernel(
    const float* __restrict__ ce, const float* __restrict__ g,
    const float* __restrict__ costs, float* __restrict__ out)
{
    float cv[KK];
#pragma unroll
    for (int k = 0; k < KK; ++k) cv[k] = costs[k];   // scalar loads

    float acc = 0.f;
#pragma unroll 2
    for (int b = threadIdx.x; b < BB; b += 1024) {
        float p = 1.f, gs = 0.f;
        float cost = cv[EE];
        int   taken = 0;
#pragma unroll
        for (int e = 0; e < EE; ++e) {
            const float ge  = g[b * EE + e];
            gs += p * ge * ce[b * KK + e];
            p  *= (1.f - ge);
            if (!taken && ge > 0.5f) { cost = cv[e]; taken = 1; }
        }
        gs += p * ce[b * KK + EE];             // p == p_last
        acc += 0.5f * gs + 0.5f * cost;        // (1-ALPHA)=ALPHA=0.5
    }

    // wave reduce
#pragma unroll
    for (int off = 32; off > 0; off >>= 1) acc += __shfl_xor(acc, off);

    __shared__ float ps[16];
    if ((threadIdx.x & 63) == 0) ps[threadIdx.x >> 6] = acc;
    __syncthreads();
    if (threadIdx.x == 0) {
        float t = 0.f;
#pragma unroll
        for (int w = 0; w < 16; ++w) t += ps[w];
        out[0] = t;
    }
}

extern "C" void kernel_launch(void* const* d_in, const int* in_sizes, int n_in,
                              void* d_out, int out_size, void* d_ws, size_t ws_size,
                              hipStream_t stream)
{
    const int*   ys    = (const int*)  d_in[0];
    const float* yh    = (const float*)d_in[1];
    const float* g     = (const float*)d_in[2];
    const float* costs = (const float*)d_in[3];
    float* out = (float*)d_out;
    float* ce  = (float*)d_ws;          // BB*KK floats = 192 KiB scratch

    ce_kernel<<<(BB * KK) / 4, 256, 0, stream>>>(yh, ys, ce);
    gate_reduce_kernel<<<1, 1024, 0, stream>>>(ce, g, costs, out);
}

// Round 4
// 274.503 us; speedup vs baseline: 1.0253x; 1.0253x over previous
//
#include <hip/hip_runtime.h>
#include <math.h>

#define BB 8192
#define KK 6
#define EE 5    // K-1
#define CC 1000
#define NV4 250 // CC/4 float4 per row
#define NBLK ((BB * KK) / 4)   // 12288 blocks, 4 waves (rows) each

// ------------- Fused kernel: CE + inline gate weight per row ---------------
// One wave per (b,k) row; 4 waves per 256-thread block. The gate weight
// w[b,k] = g[b,k] * prod_{j<k}(1-g[b,j])   (k < 5)
//        = prod_{j<5}(1-g[b,j])            (k = 5)
// depends only on g, so each wave computes its own weighted contribution
// 0.5*w*ce independently; the k==0 wave adds the 0.5*cost(b) term.
__global__ __launch_bounds__(256) void fused_ce_gate_kernel(
    const float* __restrict__ yh, const int* __restrict__ ys,
    const float* __restrict__ g, const float* __restrict__ costs,
    float* __restrict__ partial)
{
    const int wid  = (blockIdx.x * 256 + threadIdx.x) >> 6;  // row id = b*K+k
    const int lane = threadIdx.x & 63;
    const int b    = wid / KK;           // magic-mul division
    const int k    = wid - b * KK;       // wave-uniform

    const size_t row = (size_t)wid * CC;
    const float4* rp = (const float4*)(yh + row);

    // early broadcast loads (latency overlaps the streaming loads below)
    const int   y  = ys[wid];
    const float xy = yh[row + (size_t)y];
    float gv[EE];
#pragma unroll
    for (int e = 0; e < EE; ++e) gv[e] = g[b * EE + e];

    const float NEG = -__builtin_inff();
    float4 r[4];
#pragma unroll
    for (int i = 0; i < 4; ++i) {
        const int idx = lane + 64 * i;
        if (idx < NV4) r[i] = rp[idx];
        else           r[i] = make_float4(NEG, NEG, NEG, NEG);
    }

    // row max
    float mx = NEG;
#pragma unroll
    for (int i = 0; i < 4; ++i)
        mx = fmaxf(mx, fmaxf(fmaxf(r[i].x, r[i].y), fmaxf(r[i].z, r[i].w)));
#pragma unroll
    for (int off = 32; off > 0; off >>= 1)
        mx = fmaxf(mx, __shfl_xor(mx, off));

    // sum exp(x - max); exp(-inf - mx) = 0 handles the 6 pad slots
    float s = 0.f;
#pragma unroll
    for (int i = 0; i < 4; ++i) {
        s += __expf(r[i].x - mx);
        s += __expf(r[i].y - mx);
        s += __expf(r[i].z - mx);
        s += __expf(r[i].w - mx);
    }
#pragma unroll
    for (int off = 32; off > 0; off >>= 1)
        s += __shfl_xor(s, off);

    __shared__ float ps[4];
    if (lane == 0) {
        const float ce = mx + __logf(s) - xy;

        // gate weight (k is wave-uniform; pure cndmask chain)
        float pr = 1.f;
#pragma unroll
        for (int j = 0; j < EE; ++j) pr *= (j < k ? (1.f - gv[j]) : 1.f);
        const float w = (k < EE) ? pr * gv[k] : pr;

        float contrib = 0.5f * w * ce;       // (1-ALPHA) = 0.5
        if (k == 0) {                        // once per sample: exit cost
            float cost = costs[EE];
#pragma unroll
            for (int e = EE - 1; e >= 0; --e)
                if (gv[e] > 0.5f) cost = costs[e];
            contrib += 0.5f * cost;          // ALPHA = 0.5
        }
        ps[threadIdx.x >> 6] = contrib;
    }
    __syncthreads();
    if (threadIdx.x == 0)
        partial[blockIdx.x] = ps[0] + ps[1] + ps[2] + ps[3];
}

// ---------------- Deterministic final reduction (1 block) ------------------
__global__ __launch_bounds__(1024) void reduce_kernel(
    const float* __restrict__ partial, float* __restrict__ out)
{
    float s = 0.f;
#pragma unroll
    for (int i = threadIdx.x; i < NBLK; i += 1024) s += partial[i];
#pragma unroll
    for (int off = 32; off > 0; off >>= 1) s += __shfl_xor(s, off);

    __shared__ float ps[16];
    if ((threadIdx.x & 63) == 0) ps[threadIdx.x >> 6] = s;
    __syncthreads();
    if (threadIdx.x == 0) {
        float t = 0.f;
#pragma unroll
        for (int w = 0; w < 16; ++w) t += ps[w];
        out[0] = t;
    }
}

extern "C" void kernel_launch(void* const* d_in, const int* in_sizes, int n_in,
                              void* d_out, int out_size, void* d_ws, size_t ws_size,
                              hipStream_t stream)
{
    const int*   ys    = (const int*)  d_in[0];
    const float* yh    = (const float*)d_in[1];
    const float* g     = (const float*)d_in[2];
    const float* costs = (const float*)d_in[3];
    float* out     = (float*)d_out;
    float* partial = (float*)d_ws;      // NBLK floats = 48 KiB scratch

    fused_ce_gate_kernel<<<NBLK, 256, 0, stream>>>(yh, ys, g, costs, partial);
    reduce_kernel<<<1, 1024, 0, stream>>>(partial, out);
}